// Round 1
// baseline (577.521 us; speedup 1.0000x reference)
//
#include <hip/hip_runtime.h>

#define WD   192
#define HD   192
#define HWD  (WD*HD)
#define NCH  64
#define NOUT 64
#define NK   5

// Reads rot on-device, emits 5 (dr,dc) tap offsets into ws.
// kernel_type=0 (skel): taps k=0..3 at _RING[(2k+off)%8], tap 4 = center.
__global__ void prep_taps_k(const int* __restrict__ rot, int* __restrict__ taps) {
    const int ring_r[8] = {0,0,1,2,2,2,1,0};
    const int ring_c[8] = {1,2,2,2,1,0,0,0};
    int off = ((rot[0] % 8) + 8) % 8;   // step = 8/kernel_rot = 1
    #pragma unroll
    for (int k = 0; k < 4; ++k) {
        int p = (2*k + off) & 7;
        taps[2*k]   = ring_r[p] - 1;    // dr in {-1,0,1}
        taps[2*k+1] = ring_c[p] - 1;    // dc in {-1,0,1}
    }
    taps[8] = 0; taps[9] = 0;           // center tap
}

__global__ __launch_bounds__(256) void rconv_f32_k(
    const float* __restrict__ x, const float* __restrict__ w,
    const int* __restrict__ taps, float* __restrict__ out) {
    __shared__ int st[2*NK];
    if (threadIdx.x < 2*NK) st[threadIdx.x] = taps[threadIdx.x];
    __syncthreads();

    const int pix = blockIdx.x * 256 + threadIdx.x;  // 0..36863 (uniform h per wave: 192 = 3 waves/row)
    const int o0  = blockIdx.y * 4;                  // wave-uniform -> scalar weight loads
    const int n   = blockIdx.z;
    const int h  = pix / WD;
    const int ww = pix - h * WD;

    int  offk[NK];
    bool val[NK];
    #pragma unroll
    for (int k = 0; k < NK; ++k) {
        int hh = h  + st[2*k];
        int cc = ww + st[2*k+1];
        val[k]  = (hh >= 0) && (hh < HD) && (cc >= 0) && (cc < WD);
        offk[k] = hh * WD + cc;
    }

    const float* __restrict__ xn = x + (size_t)n * NCH * HWD;
    float acc0 = 0.f, acc1 = 0.f, acc2 = 0.f, acc3 = 0.f;

    for (int c = 0; c < NCH; ++c) {
        const float* __restrict__ xc = xn + (size_t)c * HWD;
        float xv[NK];
        #pragma unroll
        for (int k = 0; k < NK; ++k)
            xv[k] = val[k] ? xc[offk[k]] : 0.f;
        // weight layout [O][C][5]; o0,c,k all wave-uniform -> s_load path
        const float* wr = w + (size_t)o0 * (NCH*NK) + c * NK;
        #pragma unroll
        for (int k = 0; k < NK; ++k) {
            acc0 = fmaf(xv[k], wr[k],               acc0);
            acc1 = fmaf(xv[k], wr[NCH*NK + k],      acc1);
            acc2 = fmaf(xv[k], wr[2*NCH*NK + k],    acc2);
            acc3 = fmaf(xv[k], wr[3*NCH*NK + k],    acc3);
        }
    }
    size_t obase = ((size_t)n * NOUT + o0) * HWD + pix;
    out[obase]          = acc0;
    out[obase + HWD]    = acc1;
    out[obase + 2*HWD]  = acc2;
    out[obase + 3*HWD]  = acc3;
}

extern "C" void kernel_launch(void* const* d_in, const int* in_sizes, int n_in,
                              void* d_out, int out_size, void* d_ws, size_t ws_size,
                              hipStream_t stream) {
    const float* x  = (const float*)d_in[0];
    const float* w  = (const float*)d_in[1];
    const int* rot  = (const int*)d_in[2];
    float* out      = (float*)d_out;
    int* taps       = (int*)d_ws;

    const int nbatch = in_sizes[0] / (NCH * HWD);   // = 16

    hipLaunchKernelGGL(prep_taps_k, dim3(1), dim3(1), 0, stream, rot, taps);
    dim3 grid(HWD/256, NOUT/4, nbatch);
    hipLaunchKernelGGL(rconv_f32_k, grid, dim3(256), 0, stream, x, w, taps, out);
}

// Round 2
// 222.659 us; speedup vs baseline: 2.5937x; 2.5937x over previous
//
#include <hip/hip_runtime.h>

#define WD   192
#define HD   192
#define HWD  (WD*HD)
#define NCH  64
#define NOUT 64
#define NK   5
#define TP   256          // output pixels per block
#define SW   648          // staged pixels: [p0-196, p0+452)
#define SPAD 40           // LDS row stride in ushort (80 B = 5*16B -> b128-aligned)
#define CCH  32           // channels per staged chunk

typedef __attribute__((ext_vector_type(8))) short short8;
typedef __attribute__((ext_vector_type(4))) float f32x4;

__device__ inline ushort f2bf(float f) {
  union { float f; unsigned u; } xx; xx.f = f;
  unsigned u = xx.u;
  return (ushort)((u + 0x7FFFu + ((u >> 16) & 1u)) >> 16);   // RNE
}

// taps[0..4] = linear offset dr*192+dc ; taps[5..9] = dr ; taps[10..14] = dc
__global__ void prep_taps_k(const int* __restrict__ rot, int* __restrict__ taps) {
  const int ring_r[8] = {0,0,1,2,2,2,1,0};
  const int ring_c[8] = {1,2,2,2,1,0,0,0};
  int off = ((rot[0] % 8) + 8) % 8;   // step = 8/kernel_rot = 1
  for (int k = 0; k < 4; ++k) {
    int p = (2*k + off) & 7;
    int dr = ring_r[p] - 1, dc = ring_c[p] - 1;
    taps[k] = dr * WD + dc; taps[5 + k] = dr; taps[10 + k] = dc;
  }
  taps[4] = 0; taps[9] = 0; taps[14] = 0;   // center tap
}

__global__ __launch_bounds__(256, 3) void rconv_mfma_k(
    const float* __restrict__ x, const float* __restrict__ w,
    const int* __restrict__ taps, float* __restrict__ out) {
  __shared__ ushort lds[SW][SPAD];

  const int tid  = threadIdx.x;
  const int lane = tid & 63;
  const int wid  = tid >> 6;      // 0..3 -> o-range
  const int l15  = lane & 15;
  const int g    = lane >> 4;     // 0..3
  const int p0   = blockIdx.x * TP;
  const int n    = blockIdx.y;
  const int o0   = wid * 16;

  int stap0 = 196 + taps[0], stap1 = 196 + taps[1], stap2 = 196 + taps[2],
      stap3 = 196 + taps[3], stap4 = 196 + taps[4];

  // A fragments (W in registers): element j of lane (o=l15, g) = W[o0+l15][ch*32+8g+j][kk]
  // Same (g,j)->k map as B fragments below => correct for any HW canonical k-layout.
  short8 a[2][NK];
  #pragma unroll
  for (int ch = 0; ch < 2; ++ch) {
    #pragma unroll
    for (int kk = 0; kk < NK; ++kk) {
      short8 t;
      #pragma unroll
      for (int j = 0; j < 8; ++j) {
        int c = ch * CCH + 8 * g + j;
        t[j] = (short)f2bf(w[(size_t)(o0 + l15) * (NCH * NK) + c * NK + kk]);
      }
      a[ch][kk] = t;
    }
  }

  f32x4 acc[16];
  #pragma unroll
  for (int pt = 0; pt < 16; ++pt) acc[pt] = (f32x4){0.f, 0.f, 0.f, 0.f};

  const float* xn = x + (size_t)n * NCH * HWD;

  for (int ch = 0; ch < 2; ++ch) {
    __syncthreads();
    // stage 32 channels x 648 pixels as bf16 into [pix][c] (c-contiguous)
    #pragma unroll
    for (int it = 0; it < 2; ++it) {
      int cc = it * 16 + wid * 4;                       // within-chunk c base
      const float* xr = xn + (size_t)(ch * CCH + cc) * HWD;
      #pragma unroll
      for (int j = 0; j < 11; ++j) {
        int s = j * 64 + lane;
        if (s < SW) {
          int pg = p0 - 196 + s;
          pg = min(max(pg, 0), HWD - 1);   // clamp: garbage only feeds border pixels (fixed later)
          ushort4 v;
          v.x = f2bf(xr[pg]);
          v.y = f2bf(xr[HWD + pg]);
          v.z = f2bf(xr[2 * HWD + pg]);
          v.w = f2bf(xr[3 * HWD + pg]);
          *reinterpret_cast<ushort4*>(&lds[s][cc]) = v;
        }
      }
    }
    __syncthreads();

    #pragma unroll
    for (int pt = 0; pt < 16; ++pt) {
      int sb = pt * 16 + l15;
      int g8 = g * 8;
      short8 b0 = *reinterpret_cast<const short8*>(&lds[sb + stap0][g8]);
      short8 b1 = *reinterpret_cast<const short8*>(&lds[sb + stap1][g8]);
      short8 b2 = *reinterpret_cast<const short8*>(&lds[sb + stap2][g8]);
      short8 b3 = *reinterpret_cast<const short8*>(&lds[sb + stap3][g8]);
      short8 b4 = *reinterpret_cast<const short8*>(&lds[sb + stap4][g8]);
      acc[pt] = __builtin_amdgcn_mfma_f32_16x16x32_bf16(a[ch][0], b0, acc[pt], 0, 0, 0);
      acc[pt] = __builtin_amdgcn_mfma_f32_16x16x32_bf16(a[ch][1], b1, acc[pt], 0, 0, 0);
      acc[pt] = __builtin_amdgcn_mfma_f32_16x16x32_bf16(a[ch][2], b2, acc[pt], 0, 0, 0);
      acc[pt] = __builtin_amdgcn_mfma_f32_16x16x32_bf16(a[ch][3], b3, acc[pt], 0, 0, 0);
      acc[pt] = __builtin_amdgcn_mfma_f32_16x16x32_bf16(a[ch][4], b4, acc[pt], 0, 0, 0);
    }
  }

  // C/D layout: col = lane&15 (pixel), row = 4*(lane>>4) + reg (o)
  size_t ob = ((size_t)(n * NOUT + o0 + 4 * g)) * HWD + p0 + l15;
  #pragma unroll
  for (int pt = 0; pt < 16; ++pt) {
    #pragma unroll
    for (int r = 0; r < 4; ++r)
      out[ob + (size_t)r * HWD + pt * 16] = acc[pt][r];
  }
}

// Exact fp32 recompute of the 764 border pixels per image (overwrites main's garbage)
__global__ __launch_bounds__(256) void border_fix_k(
    const float* __restrict__ x, const float* __restrict__ w,
    const int* __restrict__ taps, float* __restrict__ out) {
  int b = blockIdx.x * 256 + threadIdx.x;
  if (b >= 4 * WD - 4) return;   // 764 border pixels
  int h, ww;
  if (b < WD)            { h = 0;                    ww = b; }
  else if (b < 2 * WD)   { h = HD - 1;               ww = b - WD; }
  else if (b < 2*WD + (HD-2)) { h = b - 2*WD + 1;    ww = 0; }
  else                   { h = b - (2*WD + HD-2) + 1; ww = WD - 1; }

  const int o0 = blockIdx.y * 4;
  const int n  = blockIdx.z;

  int offk[NK]; bool val[NK];
  #pragma unroll
  for (int k = 0; k < NK; ++k) {
    int hh = h + taps[5 + k], cc = ww + taps[10 + k];
    val[k]  = (hh >= 0) && (hh < HD) && (cc >= 0) && (cc < WD);
    offk[k] = hh * WD + cc;
  }
  const float* xn = x + (size_t)n * NCH * HWD;
  float a0 = 0.f, a1 = 0.f, a2 = 0.f, a3 = 0.f;
  for (int c = 0; c < NCH; ++c) {
    const float* xc = xn + (size_t)c * HWD;
    float xv[NK];
    #pragma unroll
    for (int k = 0; k < NK; ++k) xv[k] = val[k] ? xc[offk[k]] : 0.f;
    const float* wr = w + (size_t)o0 * (NCH * NK) + c * NK;
    #pragma unroll
    for (int k = 0; k < NK; ++k) {
      a0 = fmaf(xv[k], wr[k],                a0);
      a1 = fmaf(xv[k], wr[NCH*NK + k],       a1);
      a2 = fmaf(xv[k], wr[2*NCH*NK + k],     a2);
      a3 = fmaf(xv[k], wr[3*NCH*NK + k],     a3);
    }
  }
  int pix = h * WD + ww;
  size_t ob = ((size_t)(n * NOUT + o0)) * HWD + pix;
  out[ob]           = a0;
  out[ob + HWD]     = a1;
  out[ob + 2*HWD]   = a2;
  out[ob + 3*HWD]   = a3;
}

extern "C" void kernel_launch(void* const* d_in, const int* in_sizes, int n_in,
                              void* d_out, int out_size, void* d_ws, size_t ws_size,
                              hipStream_t stream) {
  const float* x = (const float*)d_in[0];
  const float* w = (const float*)d_in[1];
  const int* rot = (const int*)d_in[2];
  float* out     = (float*)d_out;
  int* taps      = (int*)d_ws;

  const int nbatch = in_sizes[0] / (NCH * HWD);   // 16

  hipLaunchKernelGGL(prep_taps_k, dim3(1), dim3(1), 0, stream, rot, taps);
  hipLaunchKernelGGL(rconv_mfma_k, dim3(HWD / TP, nbatch), dim3(256), 0, stream,
                     x, w, taps, out);
  hipLaunchKernelGGL(border_fix_k, dim3(3, NOUT / 4, nbatch), dim3(256), 0, stream,
                     x, w, taps, out);
}

// Round 3
// 89.793 us; speedup vs baseline: 6.4317x; 2.4797x over previous
//
#include <hip/hip_runtime.h>

#define WD   192
#define HD   192
#define HWD  (WD*HD)
#define NCH  64
#define NOUT 64
#define NK   5
#define BAND 12            // rows per block
#define SLOTS 4            // ring slots (rows)
#define COLS 194           // 1 zero-pad + 192 + 1 zero-pad
#define RSTR 72            // ushorts per pixel entry (64 ch + 8 pad = 144 B)

typedef __attribute__((ext_vector_type(8))) short short8;
typedef __attribute__((ext_vector_type(4))) float f32x4;

__device__ inline ushort f2bf(float f) {
  union { float f; unsigned u; } xx; xx.f = f;
  unsigned u = xx.u;
  return (ushort)((u + 0x7FFFu + ((u >> 16) & 1u)) >> 16);   // RNE
}

// taps[5..9] = dr ; taps[10..14] = dc   (runtime rot read on-device)
__global__ void prep_taps_k(const int* __restrict__ rot, int* __restrict__ taps) {
  const int ring_r[8] = {0,0,1,2,2,2,1,0};
  const int ring_c[8] = {1,2,2,2,1,0,0,0};
  int off = ((rot[0] % 8) + 8) % 8;   // step = 8/kernel_rot = 1
  for (int k = 0; k < 4; ++k) {
    int p = (2*k + off) & 7;
    taps[k] = 0; taps[5 + k] = ring_r[p] - 1; taps[10 + k] = ring_c[p] - 1;
  }
  taps[4] = 0; taps[9] = 0; taps[14] = 0;   // center tap
}

__global__ __launch_bounds__(512, 2) void rconv_ring_k(
    const float* __restrict__ x, const float* __restrict__ w,
    const int* __restrict__ taps, float* __restrict__ out) {
  __shared__ ushort lds[SLOTS][COLS][RSTR];   // 111,744 B

  const int tid  = threadIdx.x;
  const int lane = tid & 63;
  const int wv   = tid >> 6;        // 0..7
  const int l15  = lane & 15;
  const int g    = lane >> 4;       // 0..3
  const int r0   = blockIdx.x * BAND;
  const int n    = blockIdx.y;
  const int o0w  = (wv & 1) * 32;   // o-half owned by this wave
  const int wq   = wv >> 1;         // pixel quarter (48 pix)

  int dr[NK], dc[NK];
  #pragma unroll
  for (int k = 0; k < NK; ++k) { dr[k] = taps[5 + k]; dc[k] = taps[10 + k]; }

  // A fragments: W[o0w+ot*16+l15][kc*32+g*8+j][k]  (same (g,j)->k map as B)
  short8 a[2][2][NK];
  #pragma unroll
  for (int ot = 0; ot < 2; ++ot)
    #pragma unroll
    for (int kc = 0; kc < 2; ++kc)
      #pragma unroll
      for (int k = 0; k < NK; ++k) {
        short8 t;
        #pragma unroll
        for (int j = 0; j < 8; ++j)
          t[j] = (short)f2bf(w[(size_t)(o0w + ot*16 + l15) * (NCH*NK)
                               + (kc*32 + g*8 + j) * NK + k]);
        a[ot][kc][k] = t;
      }

  // staging: wave wv owns channels [wv*8, wv*8+8)
  const float* xn = x + ((size_t)n * NCH + wv * 8) * HWD;

  auto stage_load = [&](int gr, float v[3][8]) {
    bool vr = (gr >= 0) && (gr < HD);
    if (vr) {
      const float* xr = xn + (size_t)gr * WD;
      #pragma unroll
      for (int i = 0; i < 3; ++i)
        #pragma unroll
        for (int j = 0; j < 8; ++j)
          v[i][j] = xr[(size_t)j * HWD + i * 64 + lane];
    } else {
      #pragma unroll
      for (int i = 0; i < 3; ++i)
        #pragma unroll
        for (int j = 0; j < 8; ++j) v[i][j] = 0.f;
    }
  };
  auto stage_write = [&](int gr, const float v[3][8]) {
    int s = gr & 3;
    #pragma unroll
    for (int i = 0; i < 3; ++i) {
      short8 t;
      #pragma unroll
      for (int j = 0; j < 8; ++j) t[j] = (short)f2bf(v[i][j]);
      *reinterpret_cast<short8*>(&lds[s][1 + i * 64 + lane][wv * 8]) = t;
    }
    if (lane < 2) {   // zero the left/right pad pixels (cols 0 and 193)
      short8 z = (short8){0,0,0,0,0,0,0,0};
      *reinterpret_cast<short8*>(&lds[s][lane * (COLS - 1)][wv * 8]) = z;
    }
  };

  // prologue: rows r0-1, r0, r0+1
  {
    float v[3][8];
    stage_load(r0 - 1, v); stage_write(r0 - 1, v);
    stage_load(r0,     v); stage_write(r0,     v);
    stage_load(r0 + 1, v); stage_write(r0 + 1, v);
  }
  __syncthreads();

  for (int r = r0; r < r0 + BAND; ++r) {
    // 1. issue next-row staging loads early (hide HBM latency under MFMA)
    float v[3][8];
    const bool do_stage = (r + 2 <= r0 + BAND);
    if (do_stage) stage_load(r + 2, v);

    // 2. compute row r from slots (r-1, r, r+1)
    const ushort* bp[NK];
    #pragma unroll
    for (int k = 0; k < NK; ++k)
      bp[k] = &lds[(r + dr[k]) & 3][wq * 48 + dc[k] + 1 + l15][g * 8];

    f32x4 acc[3][2];
    #pragma unroll
    for (int t = 0; t < 3; ++t) {
      acc[t][0] = (f32x4){0.f, 0.f, 0.f, 0.f};
      acc[t][1] = (f32x4){0.f, 0.f, 0.f, 0.f};
    }

    #pragma unroll
    for (int t = 0; t < 3; ++t)
      #pragma unroll
      for (int k = 0; k < NK; ++k) {
        short8 b0 = *reinterpret_cast<const short8*>(bp[k] + t * 16 * RSTR);
        short8 b1 = *reinterpret_cast<const short8*>(bp[k] + t * 16 * RSTR + 32);
        acc[t][0] = __builtin_amdgcn_mfma_f32_16x16x32_bf16(a[0][0][k], b0, acc[t][0], 0, 0, 0);
        acc[t][1] = __builtin_amdgcn_mfma_f32_16x16x32_bf16(a[1][0][k], b0, acc[t][1], 0, 0, 0);
        acc[t][0] = __builtin_amdgcn_mfma_f32_16x16x32_bf16(a[0][1][k], b1, acc[t][0], 0, 0, 0);
        acc[t][1] = __builtin_amdgcn_mfma_f32_16x16x32_bf16(a[1][1][k], b1, acc[t][1], 0, 0, 0);
      }

    // 3. store row r: D col = l15 (pixel), row = 4g+q (o)
    size_t ob = ((size_t)(n * NOUT + o0w + 4 * g) * HD + r) * WD + wq * 48 + l15;
    #pragma unroll
    for (int t = 0; t < 3; ++t)
      #pragma unroll
      for (int ot = 0; ot < 2; ++ot)
        #pragma unroll
        for (int q = 0; q < 4; ++q)
          out[ob + (size_t)(ot * 16 + q) * HWD + t * 16] = acc[t][ot][q];

    // 4. convert + LDS-write the prefetched row into slot (r+2)&3
    if (do_stage) stage_write(r + 2, v);
    __syncthreads();
  }
}

extern "C" void kernel_launch(void* const* d_in, const int* in_sizes, int n_in,
                              void* d_out, int out_size, void* d_ws, size_t ws_size,
                              hipStream_t stream) {
  const float* x = (const float*)d_in[0];
  const float* w = (const float*)d_in[1];
  const int* rot = (const int*)d_in[2];
  float* out     = (float*)d_out;
  int* taps      = (int*)d_ws;

  const int nbatch = in_sizes[0] / (NCH * HWD);   // 16

  hipLaunchKernelGGL(prep_taps_k, dim3(1), dim3(1), 0, stream, rot, taps);
  hipLaunchKernelGGL(rconv_ring_k, dim3(HD / BAND, nbatch), dim3(512), 0, stream,
                     x, w, taps, out);
}